// Round 1
// baseline (5123.215 us; speedup 1.0000x reference)
//
#include <hip/hip_runtime.h>
#include <math.h>

#define S_TOK 1024
#define Dm    2048
#define Ee    8
#define Hh    6
#define DKk   256
#define DVv   512
#define KD    1536
#define VD    3072
#define CAP   1024

// ---------------------------------------------------------------- router ----
__global__ void router_kernel(const float* __restrict__ hidden,
                              const float* __restrict__ gate_w,
                              int* __restrict__ sel01, float* __restrict__ w01)
{
    int t = blockIdx.x;
    int lane = threadIdx.x;                      // 64 threads
    const float* hr = hidden + (size_t)t * Dm;
    float h[32];
#pragma unroll
    for (int i = 0; i < 32; ++i) h[i] = hr[lane + 64 * i];
    float logit[8];
#pragma unroll
    for (int e = 0; e < 8; ++e) {
        float acc = 0.f;
#pragma unroll
        for (int i = 0; i < 32; ++i) acc += h[i] * gate_w[(size_t)(lane + 64 * i) * 8 + e];
#pragma unroll
        for (int off = 1; off < 64; off <<= 1) acc += __shfl_xor(acc, off, 64);
        logit[e] = acc;
    }
    if (lane == 0) {
        int i0 = 0;
#pragma unroll
        for (int e = 1; e < 8; ++e) if (logit[e] > logit[i0]) i0 = e;
        int i1 = (i0 == 0) ? 1 : 0;
#pragma unroll
        for (int e = 0; e < 8; ++e) if (e != i0 && logit[e] > logit[i1]) i1 = e;
        float w0 = 1.f / (1.f + expf(logit[i1] - logit[i0]));   // renormalized top-2 softmax
        sel01[2 * t] = i0; sel01[2 * t + 1] = i1;
        w01[2 * t] = w0;   w01[2 * t + 1] = 1.f - w0;
    }
}

// -------------------------------------------------------------- dispatch ----
// One block, 1024 threads: per expert build ordered token list (stable in t),
// compact global positions, counts, bases, and token->(expert slot) map.
__global__ void dispatch_kernel(const int* __restrict__ sel01,
                                int* __restrict__ list_c, int* __restrict__ posg,
                                int* __restrict__ cnt, int* __restrict__ basearr)
{
    __shared__ int ps[1024];
    __shared__ int sbase;
    int t = threadIdx.x;
    int s0 = sel01[2 * t], s1 = sel01[2 * t + 1];
    if (t == 0) sbase = 0;
    __syncthreads();
    for (int e = 0; e < 8; ++e) {
        int flag  = (s0 == e || s1 == e) ? 1 : 0;
        int kslot = (s0 == e) ? 0 : 1;
        ps[t] = flag;
        __syncthreads();
        for (int off = 1; off < 1024; off <<= 1) {
            int v = (t >= off) ? ps[t - off] : 0;
            __syncthreads();
            ps[t] += v;
            __syncthreads();
        }
        int total = ps[1023];
        int b = sbase;
        if (flag) {
            int pos = b + ps[t] - 1;
            list_c[pos] = t;
            posg[2 * t + kslot] = pos;
        }
        __syncthreads();
        if (t == 0) { cnt[e] = total; basearr[e] = b; sbase = b + total; }
        __syncthreads();
    }
}

// ------------------------------------------------------------- fp32 GEMM ----
#define GBM 128
#define GBN 128
#define GBK 16

template<bool GATHER>
__device__ __forceinline__ void gemm_body(const float* __restrict__ A, int lda,
                                          const float* __restrict__ B, int ldb,
                                          float* __restrict__ C, int ldc,
                                          int M, int D, int m0, int n0,
                                          const int* __restrict__ ridx)
{
    __shared__ float As[GBK][GBM + 4];
    __shared__ float Bs[GBK][GBN + 4];
    int tid = threadIdx.x;
    int tx = tid & 15, ty = tid >> 4;
    float acc[8][8];
#pragma unroll
    for (int i = 0; i < 8; ++i)
#pragma unroll
        for (int j = 0; j < 8; ++j) acc[i][j] = 0.f;

    const float* aptr[2]; bool aval[2];
#pragma unroll
    for (int i = 0; i < 2; ++i) {
        int fidx = tid + i * 256;
        int row = fidx >> 2;
        int c4 = (fidx & 3) * 4;
        int m = m0 + row;
        bool val = m < M;
        int gr = val ? (GATHER ? ridx[m] : m) : 0;
        aval[i] = val;
        aptr[i] = A + (size_t)gr * lda + c4;
    }
    const float* bptr[2];
#pragma unroll
    for (int i = 0; i < 2; ++i) {
        int fidx = tid + i * 256;
        int kr = fidx >> 5;
        int c4 = (fidx & 31) * 4;
        bptr[i] = B + (size_t)kr * ldb + n0 + c4;
    }

    for (int k0 = 0; k0 < D; k0 += GBK) {
#pragma unroll
        for (int i = 0; i < 2; ++i) {
            int fidx = tid + i * 256;
            int row = fidx >> 2;
            int c4 = (fidx & 3) * 4;
            float4 av = make_float4(0.f, 0.f, 0.f, 0.f);
            if (aval[i]) av = *(const float4*)(aptr[i] + k0);
            As[c4 + 0][row] = av.x; As[c4 + 1][row] = av.y;
            As[c4 + 2][row] = av.z; As[c4 + 3][row] = av.w;
        }
#pragma unroll
        for (int i = 0; i < 2; ++i) {
            int fidx = tid + i * 256;
            int kr = fidx >> 5;
            int c4 = (fidx & 31) * 4;
            *(float4*)&Bs[kr][c4] = *(const float4*)(bptr[i] + (size_t)k0 * ldb);
        }
        __syncthreads();
#pragma unroll
        for (int kk = 0; kk < GBK; ++kk) {
            float a[8], b[8];
            *(float4*)&a[0] = *(const float4*)&As[kk][ty * 8];
            *(float4*)&a[4] = *(const float4*)&As[kk][ty * 8 + 4];
            *(float4*)&b[0] = *(const float4*)&Bs[kk][tx * 8];
            *(float4*)&b[4] = *(const float4*)&Bs[kk][tx * 8 + 4];
#pragma unroll
            for (int i = 0; i < 8; ++i)
#pragma unroll
                for (int j = 0; j < 8; ++j)
                    acc[i][j] = fmaf(a[i], b[j], acc[i][j]);
        }
        __syncthreads();
    }
#pragma unroll
    for (int i = 0; i < 8; ++i) {
        int m = m0 + ty * 8 + i;
        if (m < M) {
            float* cr = C + (size_t)m * ldc + n0 + tx * 8;
            *(float4*)cr       = *(float4*)&acc[i][0];
            *(float4*)(cr + 4) = *(float4*)&acc[i][4];
        }
    }
}

__global__ __launch_bounds__(256)
void gemm_plain(const float* __restrict__ A, const float* __restrict__ B,
                float* __restrict__ C, int M, int D, int N)
{
    gemm_body<false>(A, D, B, N, C, N, M, D, blockIdx.x * GBM, blockIdx.y * GBN, nullptr);
}

__global__ __launch_bounds__(256)
void gemm_expert(const float* __restrict__ hidden, const float* __restrict__ W,
                 float* __restrict__ Cbase,
                 const int* __restrict__ list, const int* __restrict__ cnt,
                 const int* __restrict__ basearr, int D, int N)
{
    int e = blockIdx.z;
    int M = cnt[e];
    int m0 = blockIdx.x * GBM;
    if (m0 >= M) return;
    gemm_body<true>(hidden, D, W + (size_t)e * D * N, N,
                    Cbase + (size_t)basearr[e] * N, N,
                    M, D, m0, blockIdx.y * GBN, list + basearr[e]);
}

// ------------------------------------------- beta / g small projections ----
__global__ void ba_kernel(const float* __restrict__ hidden,
                          const float* __restrict__ b_w, const float* __restrict__ a_w,
                          const float* __restrict__ A_log, const float* __restrict__ dt_bias,
                          const int* __restrict__ list, const int* __restrict__ cnt,
                          const int* __restrict__ basearr,
                          float* __restrict__ beta_c, float* __restrict__ g_c)
{
    int j = blockIdx.x, e = blockIdx.y;
    if (j >= cnt[e]) return;
    int gpos = basearr[e] + j;
    int tok = list[gpos];
    int lane = threadIdx.x;                      // 64
    const float* hr = hidden + (size_t)tok * Dm;
    float h[32];
#pragma unroll
    for (int i = 0; i < 32; ++i) h[i] = hr[lane + 64 * i];
    for (int c = 0; c < 12; ++c) {
        int col = c % 6;
        const float* W = ((c < 6) ? b_w : a_w) + (size_t)e * Dm * 6;
        float acc = 0.f;
#pragma unroll
        for (int i = 0; i < 32; ++i) acc += h[i] * W[(size_t)(lane + 64 * i) * 6 + col];
#pragma unroll
        for (int off = 1; off < 64; off <<= 1) acc += __shfl_xor(acc, off, 64);
        if (lane == 0) {
            if (c < 6) {
                beta_c[gpos * 6 + col] = 1.f / (1.f + expf(-acc));
            } else {
                float x = acc + dt_bias[col];
                float sp = (x > 20.f) ? x : log1pf(expf(x));
                g_c[gpos * 6 + col] = -expf(A_log[col]) * sp;
            }
        }
    }
}

// -------------------------------------- causal conv4 + silu (+ l2 norm) ----
template<bool GATHER>
__global__ void conv_norm_kernel(const float* __restrict__ X,   // GATHER: token rows (qh); else compact rows
                                 const float* __restrict__ convw,
                                 const int* __restrict__ list, const int* __restrict__ cnt,
                                 const int* __restrict__ basearr,
                                 float* __restrict__ outb, float scale)
{
    int j = blockIdx.x, e = blockIdx.y, h = blockIdx.z;
    if (j >= cnt[e]) return;
    int base = basearr[e];
    int gpos = base + j;
    int c = h * DKk + threadIdx.x;               // 256 threads
    float acc = 0.f;
#pragma unroll
    for (int tau = 0; tau < 4; ++tau) {
        int jj = j - 3 + tau;
        if (jj >= 0) {
            const float* row = GATHER ? (X + (size_t)list[base + jj] * KD)
                                      : (X + (size_t)(base + jj) * KD);
            acc += row[c] * convw[c * 4 + tau];
        }
    }
    float y = acc / (1.f + expf(-acc));          // silu
    float v = y * y;
#pragma unroll
    for (int off = 1; off < 64; off <<= 1) v += __shfl_xor(v, off, 64);
    __shared__ float red[4];
    if ((threadIdx.x & 63) == 0) red[threadIdx.x >> 6] = v;
    __syncthreads();
    float total = red[0] + red[1] + red[2] + red[3];
    outb[(size_t)gpos * KD + c] = y * rsqrtf(total + 1e-6f) * scale;
}

__global__ void conv_v_kernel(const float* __restrict__ X,
                              const float* __restrict__ convw,
                              const int* __restrict__ cnt, const int* __restrict__ basearr,
                              float* __restrict__ outb)
{
    int j = blockIdx.x, e = blockIdx.y;
    if (j >= cnt[e]) return;
    int base = basearr[e];
    int gpos = base + j;
    int c = blockIdx.z * 256 + threadIdx.x;      // 12 * 256 = 3072
    float acc = 0.f;
#pragma unroll
    for (int tau = 0; tau < 4; ++tau) {
        int jj = j - 3 + tau;
        if (jj >= 0) acc += X[(size_t)(base + jj) * VD + c] * convw[c * 4 + tau];
    }
    outb[(size_t)gpos * VD + c] = acc / (1.f + expf(-acc));
}

// --------------------------------------------- gated delta rule (serial) ----
// grid (DV/64, H, E); 256 threads; thread = (kpart in 0..3, vcol in 0..63).
// Each thread holds 64 state floats of column (vb*64+vcol), k-range kpart*64..+63.
__global__ __launch_bounds__(256)
void recurrence_kernel(const float* __restrict__ qn, const float* __restrict__ kn,
                       const float* __restrict__ vc,
                       const float* __restrict__ beta_c, const float* __restrict__ g_c,
                       const int* __restrict__ cnt, const int* __restrict__ basearr,
                       float* __restrict__ o_c)
{
    int vb = blockIdx.x, h = blockIdx.y, e = blockIdx.z;
    int n = cnt[e], base = basearr[e];
    int kpart = threadIdx.x & 3;
    int vcol  = threadIdx.x >> 2;
    int v = vb * 64 + vcol;
    float4 s[16];
#pragma unroll
    for (int i = 0; i < 16; ++i) s[i] = make_float4(0.f, 0.f, 0.f, 0.f);

    for (int j = 0; j < n; ++j) {
        size_t g = (size_t)(base + j);
        float eg = expf(g_c[g * 6 + h]);
        float bt = beta_c[g * 6 + h];
        float vval = vc[g * VD + h * DVv + v];
        const float4* kr = (const float4*)(kn + g * KD + h * DKk + kpart * 64);
        const float4* qr = (const float4*)(qn + g * KD + h * DKk + kpart * 64);
        float4 kk[16];
        float pred = 0.f;
#pragma unroll
        for (int i = 0; i < 16; ++i) {
            kk[i] = kr[i];
            pred += kk[i].x * s[i].x + kk[i].y * s[i].y + kk[i].z * s[i].z + kk[i].w * s[i].w;
        }
        pred += __shfl_xor(pred, 1, 64);
        pred += __shfl_xor(pred, 2, 64);
        float delta = (vval - pred * eg) * bt;
        float out = 0.f;
#pragma unroll
        for (int i = 0; i < 16; ++i) {
            float4 q4 = qr[i];
            s[i].x = fmaf(eg, s[i].x, kk[i].x * delta);
            s[i].y = fmaf(eg, s[i].y, kk[i].y * delta);
            s[i].z = fmaf(eg, s[i].z, kk[i].z * delta);
            s[i].w = fmaf(eg, s[i].w, kk[i].w * delta);
            out += q4.x * s[i].x + q4.y * s[i].y + q4.z * s[i].z + q4.w * s[i].w;
        }
        out += __shfl_xor(out, 1, 64);
        out += __shfl_xor(out, 2, 64);
        if (kpart == 0) o_c[g * VD + h * DVv + v] = out;
    }
}

// ------------------------------- combine + gated RMSNorm (swish gate) -------
__global__ void combine_kernel(const float* __restrict__ o_c, const float* __restrict__ gg,
                               const float* __restrict__ norm_w,
                               const int* __restrict__ posg, const float* __restrict__ w01,
                               float* __restrict__ ocg)
{
    int t = blockIdx.x, h = blockIdx.y;
    int p0 = posg[2 * t], p1 = posg[2 * t + 1];
    float w0 = w01[2 * t], w1 = w01[2 * t + 1];
    int v0 = threadIdx.x, v1 = threadIdx.x + 256;
    size_t r0 = (size_t)p0 * VD + h * DVv, r1 = (size_t)p1 * VD + h * DVv;
    float a  = w0 * o_c[r0 + v0] + w1 * o_c[r1 + v0];
    float b2 = w0 * o_c[r0 + v1] + w1 * o_c[r1 + v1];
    float val = a * a + b2 * b2;
#pragma unroll
    for (int off = 1; off < 64; off <<= 1) val += __shfl_xor(val, off, 64);
    __shared__ float red[4];
    if ((threadIdx.x & 63) == 0) red[threadIdx.x >> 6] = val;
    __syncthreads();
    float total = red[0] + red[1] + red[2] + red[3];
    float rms = rsqrtf(total / 512.f + 1e-5f);
    size_t og = (size_t)t * VD + h * DVv;
    float g0 = gg[og + v0], g1 = gg[og + v1];
    ocg[og + v0] = a  * rms * norm_w[v0] * g0 / (1.f + expf(-g0));
    ocg[og + v1] = b2 * rms * norm_w[v1] * g1 / (1.f + expf(-g1));
}

// ------------------------------------------------------------------ host ----
extern "C" void kernel_launch(void* const* d_in, const int* in_sizes, int n_in,
                              void* d_out, int out_size, void* d_ws, size_t ws_size,
                              hipStream_t stream)
{
    const float* hidden   = (const float*)d_in[0];
    const float* q_w      = (const float*)d_in[1];
    const float* gate_w   = (const float*)d_in[2];
    const float* k_w      = (const float*)d_in[3];
    const float* v_w      = (const float*)d_in[4];
    const float* b_w      = (const float*)d_in[5];
    const float* a_w      = (const float*)d_in[6];
    const float* A_log    = (const float*)d_in[7];
    const float* dt_bias  = (const float*)d_in[8];
    const float* q_conv_w = (const float*)d_in[9];
    const float* k_conv_w = (const float*)d_in[10];
    const float* v_conv_w = (const float*)d_in[11];
    const float* g_w      = (const float*)d_in[12];
    const float* norm_w   = (const float*)d_in[13];
    const float* o_w      = (const float*)d_in[14];
    float* outp = (float*)d_out;

    float* f = (float*)d_ws;
    size_t off = 0;
    auto alloc = [&](size_t n) { float* p = f + off; off += n; return p; };
    float* qh     = alloc((size_t)1024 * 1536);
    float* kraw   = alloc((size_t)2048 * 1536);
    float* qn     = alloc((size_t)2048 * 1536);
    float* kn     = alloc((size_t)2048 * 1536);
    float* vraw   = alloc((size_t)2048 * 3072);   // later reused as o_c
    float* vconv  = alloc((size_t)2048 * 3072);
    float* gg     = alloc((size_t)1024 * 3072);
    float* ocg    = alloc((size_t)1024 * 3072);
    float* beta_c = alloc(2048 * 6);
    float* g_c    = alloc(2048 * 6);
    float* w01    = alloc(2048);
    int* ibase   = (int*)(f + off);
    int* sel01   = ibase;
    int* list_c  = ibase + 2048;
    int* posg    = ibase + 4096;
    int* cnt     = ibase + 6144;
    int* basearr = ibase + 6152;
    float* o_c = vraw;   // vraw dead after conv_v; recurrence output aliases it

    router_kernel<<<1024, 64, 0, stream>>>(hidden, gate_w, sel01, w01);
    dispatch_kernel<<<1, 1024, 0, stream>>>(sel01, list_c, posg, cnt, basearr);

    gemm_plain<<<dim3(8, 12), 256, 0, stream>>>(hidden, q_w, qh, 1024, 2048, 1536);
    gemm_expert<<<dim3(8, 12, 8), 256, 0, stream>>>(hidden, k_w, kraw, list_c, cnt, basearr, 2048, 1536);
    gemm_expert<<<dim3(8, 24, 8), 256, 0, stream>>>(hidden, v_w, vraw, list_c, cnt, basearr, 2048, 3072);
    ba_kernel<<<dim3(1024, 8), 64, 0, stream>>>(hidden, b_w, a_w, A_log, dt_bias,
                                                list_c, cnt, basearr, beta_c, g_c);

    conv_norm_kernel<true ><<<dim3(1024, 8, 6), 256, 0, stream>>>(qh,   q_conv_w, list_c, cnt, basearr, qn, 0.0625f);
    conv_norm_kernel<false><<<dim3(1024, 8, 6), 256, 0, stream>>>(kraw, k_conv_w, list_c, cnt, basearr, kn, 1.0f);
    conv_v_kernel<<<dim3(1024, 8, 12), 256, 0, stream>>>(vraw, v_conv_w, cnt, basearr, vconv);

    recurrence_kernel<<<dim3(8, 6, 8), 256, 0, stream>>>(qn, kn, vconv, beta_c, g_c,
                                                         cnt, basearr, o_c);

    gemm_plain<<<dim3(8, 24), 256, 0, stream>>>(hidden, g_w, gg, 1024, 2048, 3072);
    combine_kernel<<<dim3(1024, 6), 256, 0, stream>>>(o_c, gg, norm_w, posg, w01, ocg);
    gemm_plain<<<dim3(8, 16), 256, 0, stream>>>(ocg, o_w, outp, 1024, 3072, 2048);
}

// Round 2
// 2435.551 us; speedup vs baseline: 2.1035x; 2.1035x over previous
//
#include <hip/hip_runtime.h>
#include <math.h>

#define Dm    2048
#define Hh    6
#define DKk   256
#define DVv   512
#define KD    1536
#define VD    3072

typedef __attribute__((ext_vector_type(8))) __bf16 bf16x8;
typedef __attribute__((ext_vector_type(4))) float floatx4;

__device__ __forceinline__ unsigned short f2bf(float f) {
    unsigned int u = __float_as_uint(f);
    u = (u + 0x7fffu + ((u >> 16) & 1u)) >> 16;
    return (unsigned short)u;
}

__device__ __forceinline__ void gl_lds16(const void* g, void* l) {
    __builtin_amdgcn_global_load_lds((const __attribute__((address_space(1))) void*)g,
                                     (__attribute__((address_space(3))) void*)l, 16, 0, 0);
}

// ---------------------------------------------------------------- router ----
__global__ void router_kernel(const float* __restrict__ hidden,
                              const float* __restrict__ gate_w,
                              int* __restrict__ sel01, float* __restrict__ w01)
{
    int t = blockIdx.x;
    int lane = threadIdx.x;                      // 64 threads
    const float* hr = hidden + (size_t)t * Dm;
    float h[32];
#pragma unroll
    for (int i = 0; i < 32; ++i) h[i] = hr[lane + 64 * i];
    float logit[8];
#pragma unroll
    for (int e = 0; e < 8; ++e) {
        float acc = 0.f;
#pragma unroll
        for (int i = 0; i < 32; ++i) acc += h[i] * gate_w[(size_t)(lane + 64 * i) * 8 + e];
#pragma unroll
        for (int off = 1; off < 64; off <<= 1) acc += __shfl_xor(acc, off, 64);
        logit[e] = acc;
    }
    if (lane == 0) {
        int i0 = 0;
#pragma unroll
        for (int e = 1; e < 8; ++e) if (logit[e] > logit[i0]) i0 = e;
        int i1 = (i0 == 0) ? 1 : 0;
#pragma unroll
        for (int e = 0; e < 8; ++e) if (e != i0 && logit[e] > logit[i1]) i1 = e;
        float w0 = 1.f / (1.f + expf(logit[i1] - logit[i0]));
        sel01[2 * t] = i0; sel01[2 * t + 1] = i1;
        w01[2 * t] = w0;   w01[2 * t + 1] = 1.f - w0;
    }
}

// -------------------------------------------------------------- dispatch ----
__global__ void dispatch_kernel(const int* __restrict__ sel01,
                                int* __restrict__ list_c, int* __restrict__ posg,
                                int* __restrict__ cnt, int* __restrict__ basearr)
{
    __shared__ int ps[1024];
    __shared__ int sbase;
    int t = threadIdx.x;
    int s0 = sel01[2 * t], s1 = sel01[2 * t + 1];
    if (t == 0) sbase = 0;
    __syncthreads();
    for (int e = 0; e < 8; ++e) {
        int flag  = (s0 == e || s1 == e) ? 1 : 0;
        int kslot = (s0 == e) ? 0 : 1;
        ps[t] = flag;
        __syncthreads();
        for (int off = 1; off < 1024; off <<= 1) {
            int v = (t >= off) ? ps[t - off] : 0;
            __syncthreads();
            ps[t] += v;
            __syncthreads();
        }
        int total = ps[1023];
        int b = sbase;
        if (flag) {
            int pos = b + ps[t] - 1;
            list_c[pos] = t;
            posg[2 * t + kslot] = pos;
        }
        __syncthreads();
        if (t == 0) { cnt[e] = total; basearr[e] = b; sbase = b + total; }
        __syncthreads();
    }
}

// ------------------------------------------------------------ bf16 casts ----
__global__ void cast_bf16_kernel(const float* __restrict__ x, unsigned short* __restrict__ y)
{
    int i = (blockIdx.x * 256 + threadIdx.x) * 4;
    float4 a = *(const float4*)(x + i);
    ushort4 o;
    o.x = f2bf(a.x); o.y = f2bf(a.y); o.z = f2bf(a.z); o.w = f2bf(a.w);
    *(ushort4*)(y + i) = o;
}

__global__ void gather_cast_kernel(const float* __restrict__ hidden, const int* __restrict__ list,
                                   unsigned short* __restrict__ xe)
{
    int slot = blockIdx.x;
    int tok = list[slot];
    const float* src = hidden + (size_t)tok * Dm;
    unsigned short* dst = xe + (size_t)slot * Dm;
    int c = threadIdx.x * 8;
    float4 a = *(const float4*)(src + c);
    float4 b = *(const float4*)(src + c + 4);
    ushort4 o1, o2;
    o1.x = f2bf(a.x); o1.y = f2bf(a.y); o1.z = f2bf(a.z); o1.w = f2bf(a.w);
    o2.x = f2bf(b.x); o2.y = f2bf(b.y); o2.z = f2bf(b.z); o2.w = f2bf(b.w);
    *(ushort4*)(dst + c) = o1;
    *(ushort4*)(dst + c + 4) = o2;
}

// fp32 [B][K][N] -> bf16 [B][N][K]
__global__ void transpose_cast_kernel(const float* __restrict__ in, unsigned short* __restrict__ out,
                                      int K, int N)
{
    __shared__ float tile[32][33];
    int b = blockIdx.z;
    int k0 = blockIdx.x * 32, n0 = blockIdx.y * 32;
    const float* ip = in + (size_t)b * K * N;
    unsigned short* op = out + (size_t)b * K * N;
    int tx = threadIdx.x & 31, ty = threadIdx.x >> 5;   // 32 x 8
#pragma unroll
    for (int i = 0; i < 4; ++i)
        tile[ty + i * 8][tx] = ip[(size_t)(k0 + ty + i * 8) * N + n0 + tx];
    __syncthreads();
#pragma unroll
    for (int i = 0; i < 4; ++i)
        op[(size_t)(n0 + ty + i * 8) * K + k0 + tx] = f2bf(tile[tx][ty + i * 8]);
}

// ----------------------------------------------------------- bf16 GEMM ------
// C[M][N] = A[M][K] * Bt[N][K]^T, 128x128 tile, BK=32, mfma 16x16x32 bf16.
template<bool EXPERT>
__global__ __launch_bounds__(256)
void gemm_bf16(const unsigned short* __restrict__ A,
               const unsigned short* __restrict__ Bt,
               float* __restrict__ C,
               const int* __restrict__ cnt, const int* __restrict__ basearr,
               int M, int K, int N)
{
    int e = EXPERT ? blockIdx.z : 0;
    int Mloc = M, base = 0;
    if (EXPERT) {
        Mloc = cnt[e]; base = basearr[e];
        if ((int)(blockIdx.x * 128) >= Mloc) return;
    }
    int m0 = blockIdx.x * 128, n0 = blockIdx.y * 128;
    const unsigned short* Ab = A + (size_t)base * K;
    const unsigned short* Bb = Bt + (size_t)e * (size_t)K * N;
    __shared__ unsigned short As[128 * 32];
    __shared__ unsigned short Bs[128 * 32];
    int tid = threadIdx.x;
    int lane = tid & 63, wave = tid >> 6;
    const unsigned short* ga[2];
    const unsigned short* gb[2];
    unsigned short* la[2];
    unsigned short* lb[2];
#pragma unroll
    for (int j = 0; j < 2; ++j) {
        int flat = j * 256 + tid;
        int row = flat >> 2, sub = flat & 3;
        int ar = m0 + row; if (ar > Mloc - 1) ar = Mloc - 1;
        ga[j] = Ab + (size_t)ar * K + sub * 8;
        gb[j] = Bb + (size_t)(n0 + row) * K + sub * 8;
        la[j] = As + flat * 8;
        lb[j] = Bs + flat * 8;
    }
    floatx4 acc[4][4];
#pragma unroll
    for (int i = 0; i < 4; ++i)
#pragma unroll
        for (int j = 0; j < 4; ++j) acc[i][j] = (floatx4){0.f, 0.f, 0.f, 0.f};

    int wm = (wave >> 1) * 64, wn = (wave & 1) * 64;
    int fr = lane & 15, kr = (lane >> 4) * 8;

    for (int k0 = 0; k0 < K; k0 += 32) {
        gl_lds16(ga[0] + k0, la[0]);
        gl_lds16(gb[0] + k0, lb[0]);
        gl_lds16(ga[1] + k0, la[1]);
        gl_lds16(gb[1] + k0, lb[1]);
        __syncthreads();
        bf16x8 af[4], bfr[4];
#pragma unroll
        for (int f = 0; f < 4; ++f) {
            af[f]  = *(const bf16x8*)(As + (size_t)(wm + f * 16 + fr) * 32 + kr);
            bfr[f] = *(const bf16x8*)(Bs + (size_t)(wn + f * 16 + fr) * 32 + kr);
        }
#pragma unroll
        for (int fm = 0; fm < 4; ++fm)
#pragma unroll
            for (int fn = 0; fn < 4; ++fn)
                acc[fm][fn] = __builtin_amdgcn_mfma_f32_16x16x32_bf16(af[fm], bfr[fn], acc[fm][fn], 0, 0, 0);
        __syncthreads();
    }
    int rb = (lane >> 4) * 4;
#pragma unroll
    for (int fm = 0; fm < 4; ++fm) {
#pragma unroll
        for (int r = 0; r < 4; ++r) {
            int m = m0 + wm + fm * 16 + rb + r;
            if (m < Mloc) {
                float* cp = C + (size_t)(base + m) * N + n0 + wn + fr;
#pragma unroll
                for (int fn = 0; fn < 4; ++fn)
                    cp[fn * 16] = acc[fm][fn][r];
            }
        }
    }
}

// ------------------------------------------- beta / g small projections ----
__global__ void ba_kernel(const float* __restrict__ hidden,
                          const float* __restrict__ b_w, const float* __restrict__ a_w,
                          const float* __restrict__ A_log, const float* __restrict__ dt_bias,
                          const int* __restrict__ list, const int* __restrict__ cnt,
                          const int* __restrict__ basearr,
                          float* __restrict__ beta_c, float* __restrict__ g_c)
{
    int j = blockIdx.x, e = blockIdx.y;
    if (j >= cnt[e]) return;
    int gpos = basearr[e] + j;
    int tok = list[gpos];
    int lane = threadIdx.x;                      // 64
    const float* hr = hidden + (size_t)tok * Dm;
    float h[32];
#pragma unroll
    for (int i = 0; i < 32; ++i) h[i] = hr[lane + 64 * i];
    for (int c = 0; c < 12; ++c) {
        int col = c % 6;
        const float* W = ((c < 6) ? b_w : a_w) + (size_t)e * Dm * 6;
        float acc = 0.f;
#pragma unroll
        for (int i = 0; i < 32; ++i) acc += h[i] * W[(size_t)(lane + 64 * i) * 6 + col];
#pragma unroll
        for (int off = 1; off < 64; off <<= 1) acc += __shfl_xor(acc, off, 64);
        if (lane == 0) {
            if (c < 6) {
                beta_c[gpos * 6 + col] = 1.f / (1.f + expf(-acc));
            } else {
                float x = acc + dt_bias[col];
                float sp = (x > 20.f) ? x : log1pf(expf(x));
                g_c[gpos * 6 + col] = -expf(A_log[col]) * sp;
            }
        }
    }
}

// -------------------------------------- causal conv4 + silu (+ l2 norm) ----
template<bool GATHER>
__global__ void conv_norm_kernel(const float* __restrict__ X,
                                 const float* __restrict__ convw,
                                 const int* __restrict__ list, const int* __restrict__ cnt,
                                 const int* __restrict__ basearr,
                                 float* __restrict__ outb, float scale)
{
    int j = blockIdx.x, e = blockIdx.y, h = blockIdx.z;
    if (j >= cnt[e]) return;
    int base = basearr[e];
    int gpos = base + j;
    int c = h * DKk + threadIdx.x;               // 256 threads
    float acc = 0.f;
#pragma unroll
    for (int tau = 0; tau < 4; ++tau) {
        int jj = j - 3 + tau;
        if (jj >= 0) {
            const float* row = GATHER ? (X + (size_t)list[base + jj] * KD)
                                      : (X + (size_t)(base + jj) * KD);
            acc += row[c] * convw[c * 4 + tau];
        }
    }
    float y = acc / (1.f + expf(-acc));          // silu
    float v = y * y;
#pragma unroll
    for (int off = 1; off < 64; off <<= 1) v += __shfl_xor(v, off, 64);
    __shared__ float red[4];
    if ((threadIdx.x & 63) == 0) red[threadIdx.x >> 6] = v;
    __syncthreads();
    float total = red[0] + red[1] + red[2] + red[3];
    outb[(size_t)gpos * KD + c] = y * rsqrtf(total + 1e-6f) * scale;
}

__global__ void conv_v_kernel(const float* __restrict__ X,
                              const float* __restrict__ convw,
                              const int* __restrict__ cnt, const int* __restrict__ basearr,
                              float* __restrict__ outb)
{
    int j = blockIdx.x, e = blockIdx.y;
    if (j >= cnt[e]) return;
    int base = basearr[e];
    int gpos = base + j;
    int c = blockIdx.z * 256 + threadIdx.x;      // 12 * 256 = 3072
    float acc = 0.f;
#pragma unroll
    for (int tau = 0; tau < 4; ++tau) {
        int jj = j - 3 + tau;
        if (jj >= 0) acc += X[(size_t)(base + jj) * VD + c] * convw[c * 4 + tau];
    }
    outb[(size_t)gpos * VD + c] = acc / (1.f + expf(-acc));
}

// --------------------------------------------- gated delta rule (serial) ----
// grid (16, H, E); 256 threads; thread = (kpart 0..7, vcol 0..31).
// 32 state floats/thread. out = e^g (q.S_old) + (q.k) delta  -> q dead after dots.
__global__ __launch_bounds__(256)
void recurrence_kernel(const float* __restrict__ qn, const float* __restrict__ kn,
                       const float* __restrict__ vc,
                       const float* __restrict__ beta_c, const float* __restrict__ g_c,
                       const int* __restrict__ cnt, const int* __restrict__ basearr,
                       float* __restrict__ o_c)
{
    int vb = blockIdx.x, h = blockIdx.y, e = blockIdx.z;
    int n = cnt[e], base = basearr[e];
    int kpart = threadIdx.x & 7;
    int vcol  = threadIdx.x >> 3;
    int v = vb * 32 + vcol;
    const float* kb = kn + (size_t)base * KD + h * DKk + kpart * 32;
    const float* qb = qn + (size_t)base * KD + h * DKk + kpart * 32;
    const float* vp = vc + (size_t)base * VD + h * DVv + v;
    const float* gp = g_c + (size_t)base * Hh + h;
    const float* bp = beta_c + (size_t)base * Hh + h;
    float* op = o_c + (size_t)base * VD + h * DVv + v;
    float4 s[8];
#pragma unroll
    for (int i = 0; i < 8; ++i) s[i] = make_float4(0.f, 0.f, 0.f, 0.f);

    for (int j = 0; j < n; ++j) {
        const float4* krp = (const float4*)(kb + (size_t)j * KD);
        const float4* qrp = (const float4*)(qb + (size_t)j * KD);
        float4 kk[8], qq[8];
#pragma unroll
        for (int i = 0; i < 8; ++i) { kk[i] = krp[i]; qq[i] = qrp[i]; }
        float gv = gp[(size_t)j * Hh];
        float btv = bp[(size_t)j * Hh];
        float vval = vp[(size_t)j * VD];
        float4 pa = make_float4(0.f, 0.f, 0.f, 0.f);
        float4 ra = make_float4(0.f, 0.f, 0.f, 0.f);
        float4 qa = make_float4(0.f, 0.f, 0.f, 0.f);
#pragma unroll
        for (int i = 0; i < 8; ++i) {
            pa.x = fmaf(kk[i].x, s[i].x, pa.x); pa.y = fmaf(kk[i].y, s[i].y, pa.y);
            pa.z = fmaf(kk[i].z, s[i].z, pa.z); pa.w = fmaf(kk[i].w, s[i].w, pa.w);
            ra.x = fmaf(qq[i].x, s[i].x, ra.x); ra.y = fmaf(qq[i].y, s[i].y, ra.y);
            ra.z = fmaf(qq[i].z, s[i].z, ra.z); ra.w = fmaf(qq[i].w, s[i].w, ra.w);
            qa.x = fmaf(qq[i].x, kk[i].x, qa.x); qa.y = fmaf(qq[i].y, kk[i].y, qa.y);
            qa.z = fmaf(qq[i].z, kk[i].z, qa.z); qa.w = fmaf(qq[i].w, kk[i].w, qa.w);
        }
        float p  = (pa.x + pa.y) + (pa.z + pa.w);
        float r  = (ra.x + ra.y) + (ra.z + ra.w);
        float qk = (qa.x + qa.y) + (qa.z + qa.w);
#pragma unroll
        for (int m = 1; m < 8; m <<= 1) {
            p  += __shfl_xor(p,  m, 64);
            r  += __shfl_xor(r,  m, 64);
            qk += __shfl_xor(qk, m, 64);
        }
        float eg = __expf(gv);
        float delta = (vval - p * eg) * btv;
        float out = fmaf(qk, delta, eg * r);
#pragma unroll
        for (int i = 0; i < 8; ++i) {
            s[i].x = fmaf(eg, s[i].x, kk[i].x * delta);
            s[i].y = fmaf(eg, s[i].y, kk[i].y * delta);
            s[i].z = fmaf(eg, s[i].z, kk[i].z * delta);
            s[i].w = fmaf(eg, s[i].w, kk[i].w * delta);
        }
        if (kpart == 0) op[(size_t)j * VD] = out;
    }
}

// ------------------------------- combine + gated RMSNorm (swish gate) -------
__global__ void combine_kernel(const float* __restrict__ o_c, const float* __restrict__ gg,
                               const float* __restrict__ norm_w,
                               const int* __restrict__ posg, const float* __restrict__ w01,
                               unsigned short* __restrict__ ocg)
{
    int t = blockIdx.x, h = blockIdx.y;
    int p0 = posg[2 * t], p1 = posg[2 * t + 1];
    float w0 = w01[2 * t], w1 = w01[2 * t + 1];
    int v0 = threadIdx.x, v1 = threadIdx.x + 256;
    size_t r0 = (size_t)p0 * VD + h * DVv, r1 = (size_t)p1 * VD + h * DVv;
    float a  = w0 * o_c[r0 + v0] + w1 * o_c[r1 + v0];
    float b2 = w0 * o_c[r0 + v1] + w1 * o_c[r1 + v1];
    float val = a * a + b2 * b2;
#pragma unroll
    for (int off = 1; off < 64; off <<= 1) val += __shfl_xor(val, off, 64);
    __shared__ float red[4];
    if ((threadIdx.x & 63) == 0) red[threadIdx.x >> 6] = val;
    __syncthreads();
    float total = red[0] + red[1] + red[2] + red[3];
    float rms = rsqrtf(total / 512.f + 1e-5f);
    size_t og = (size_t)t * VD + h * DVv;
    float g0 = gg[og + v0], g1 = gg[og + v1];
    ocg[og + v0] = f2bf(a  * rms * norm_w[v0] * g0 / (1.f + expf(-g0)));
    ocg[og + v1] = f2bf(b2 * rms * norm_w[v1] * g1 / (1.f + expf(-g1)));
}

// ------------------------------------------------------------------ host ----
extern "C" void kernel_launch(void* const* d_in, const int* in_sizes, int n_in,
                              void* d_out, int out_size, void* d_ws, size_t ws_size,
                              hipStream_t stream)
{
    const float* hidden   = (const float*)d_in[0];
    const float* q_w      = (const float*)d_in[1];
    const float* gate_w   = (const float*)d_in[2];
    const float* k_w      = (const float*)d_in[3];
    const float* v_w      = (const float*)d_in[4];
    const float* b_w      = (const float*)d_in[5];
    const float* a_w      = (const float*)d_in[6];
    const float* A_log    = (const float*)d_in[7];
    const float* dt_bias  = (const float*)d_in[8];
    const float* q_conv_w = (const float*)d_in[9];
    const float* k_conv_w = (const float*)d_in[10];
    const float* v_conv_w = (const float*)d_in[11];
    const float* g_w      = (const float*)d_in[12];
    const float* norm_w   = (const float*)d_in[13];
    const float* o_w      = (const float*)d_in[14];
    float* outp = (float*)d_out;

    float* f = (float*)d_ws;
    size_t off = 0;
    auto alloc = [&](size_t n) { float* p = f + off; off += (n + 3) & ~(size_t)3; return p; };
    float* qh     = alloc((size_t)1024 * 1536);
    float* kraw   = alloc((size_t)2048 * 1536);
    float* qn     = alloc((size_t)2048 * 1536);
    float* kn     = alloc((size_t)2048 * 1536);
    float* vraw   = alloc((size_t)2048 * 3072);   // reused as o_c after conv_v
    float* vconv  = alloc((size_t)2048 * 3072);
    float* gg     = alloc((size_t)1024 * 3072);
    float* beta_c = alloc(2048 * 6);
    float* g_c    = alloc(2048 * 6);
    float* w01f   = alloc(2048);

    unsigned short* u = (unsigned short*)(f + off);
    size_t uoff = 0;
    auto ualloc = [&](size_t n) { unsigned short* p = u + uoff; uoff += (n + 7) & ~(size_t)7; return p; };
    unsigned short* hidden_bf = ualloc((size_t)1024 * 2048);
    unsigned short* xe_c      = ualloc((size_t)2048 * 2048);
    unsigned short* ocg       = ualloc((size_t)1024 * 3072);
    unsigned short* q_wT      = ualloc((size_t)2048 * 1536);
    unsigned short* k_wT      = ualloc((size_t)8 * 2048 * 1536);
    unsigned short* v_wT      = ualloc((size_t)8 * 2048 * 3072);
    unsigned short* g_wT      = ualloc((size_t)2048 * 3072);
    unsigned short* o_wT      = ualloc((size_t)3072 * 2048);

    int* ib      = (int*)(u + uoff);
    int* sel01   = ib;
    int* list_c  = ib + 2048;
    int* posg    = ib + 4096;
    int* cnt     = ib + 6144;
    int* basearr = ib + 6152;
    float* o_c = vraw;

    router_kernel<<<1024, 64, 0, stream>>>(hidden, gate_w, sel01, w01f);
    dispatch_kernel<<<1, 1024, 0, stream>>>(sel01, list_c, posg, cnt, basearr);

    cast_bf16_kernel<<<2048, 256, 0, stream>>>(hidden, hidden_bf);
    gather_cast_kernel<<<2048, 256, 0, stream>>>(hidden, list_c, xe_c);
    transpose_cast_kernel<<<dim3(64, 48, 1), 256, 0, stream>>>(q_w, q_wT, 2048, 1536);
    transpose_cast_kernel<<<dim3(64, 48, 8), 256, 0, stream>>>(k_w, k_wT, 2048, 1536);
    transpose_cast_kernel<<<dim3(64, 96, 8), 256, 0, stream>>>(v_w, v_wT, 2048, 3072);
    transpose_cast_kernel<<<dim3(64, 96, 1), 256, 0, stream>>>(g_w, g_wT, 2048, 3072);
    transpose_cast_kernel<<<dim3(96, 64, 1), 256, 0, stream>>>(o_w, o_wT, 3072, 2048);

    gemm_bf16<false><<<dim3(8, 12), 256, 0, stream>>>(hidden_bf, q_wT, qh, nullptr, nullptr, 1024, 2048, 1536);
    gemm_bf16<true ><<<dim3(8, 12, 8), 256, 0, stream>>>(xe_c, k_wT, kraw, cnt, basearr, 0, 2048, 1536);
    gemm_bf16<true ><<<dim3(8, 24, 8), 256, 0, stream>>>(xe_c, v_wT, vraw, cnt, basearr, 0, 2048, 3072);
    gemm_bf16<false><<<dim3(8, 24), 256, 0, stream>>>(hidden_bf, g_wT, gg, nullptr, nullptr, 1024, 2048, 3072);

    ba_kernel<<<dim3(1024, 8), 64, 0, stream>>>(hidden, b_w, a_w, A_log, dt_bias,
                                                list_c, cnt, basearr, beta_c, g_c);

    conv_norm_kernel<true ><<<dim3(1024, 8, 6), 256, 0, stream>>>(qh,   q_conv_w, list_c, cnt, basearr, qn, 0.0625f);
    conv_norm_kernel<false><<<dim3(1024, 8, 6), 256, 0, stream>>>(kraw, k_conv_w, list_c, cnt, basearr, kn, 1.0f);
    conv_v_kernel<<<dim3(1024, 8, 12), 256, 0, stream>>>(vraw, v_conv_w, cnt, basearr, vconv);

    recurrence_kernel<<<dim3(16, 6, 8), 256, 0, stream>>>(qn, kn, vconv, beta_c, g_c,
                                                          cnt, basearr, o_c);

    combine_kernel<<<dim3(1024, 6), 256, 0, stream>>>(o_c, gg, norm_w, posg, w01f, ocg);
    gemm_bf16<false><<<dim3(8, 16), 256, 0, stream>>>(ocg, o_wT, outp, nullptr, nullptr, 1024, 3072, 2048);
}

// Round 3
// 2419.480 us; speedup vs baseline: 2.1175x; 1.0066x over previous
//
#include <hip/hip_runtime.h>
#include <math.h>

#define Dm    2048
#define Hh    6
#define DKk   256
#define DVv   512
#define KD    1536
#define VD    3072

typedef __attribute__((ext_vector_type(8))) __bf16 bf16x8;
typedef __attribute__((ext_vector_type(4))) float floatx4;

__device__ __forceinline__ unsigned short f2bf(float f) {
    unsigned int u = __float_as_uint(f);
    u = (u + 0x7fffu + ((u >> 16) & 1u)) >> 16;
    return (unsigned short)u;
}

__device__ __forceinline__ void gl_lds16(const void* g, void* l) {
    __builtin_amdgcn_global_load_lds((const __attribute__((address_space(1))) void*)g,
                                     (__attribute__((address_space(3))) void*)l, 16, 0, 0);
}

// ---------------------------------------------------------------- router ----
__global__ void router_kernel(const float* __restrict__ hidden,
                              const float* __restrict__ gate_w,
                              int* __restrict__ sel01, float* __restrict__ w01)
{
    int t = blockIdx.x;
    int lane = threadIdx.x;                      // 64 threads
    const float* hr = hidden + (size_t)t * Dm;
    float h[32];
#pragma unroll
    for (int i = 0; i < 32; ++i) h[i] = hr[lane + 64 * i];
    float logit[8];
#pragma unroll
    for (int e = 0; e < 8; ++e) {
        float acc = 0.f;
#pragma unroll
        for (int i = 0; i < 32; ++i) acc += h[i] * gate_w[(size_t)(lane + 64 * i) * 8 + e];
#pragma unroll
        for (int off = 1; off < 64; off <<= 1) acc += __shfl_xor(acc, off, 64);
        logit[e] = acc;
    }
    if (lane == 0) {
        int i0 = 0;
#pragma unroll
        for (int e = 1; e < 8; ++e) if (logit[e] > logit[i0]) i0 = e;
        int i1 = (i0 == 0) ? 1 : 0;
#pragma unroll
        for (int e = 0; e < 8; ++e) if (e != i0 && logit[e] > logit[i1]) i1 = e;
        float w0 = 1.f / (1.f + expf(logit[i1] - logit[i0]));
        sel01[2 * t] = i0; sel01[2 * t + 1] = i1;
        w01[2 * t] = w0;   w01[2 * t + 1] = 1.f - w0;
    }
}

// -------------------------------------------------------------- dispatch ----
// 1024 threads = 16 waves. Ballot-based scan, 3 barriers per expert.
__global__ void dispatch_kernel(const int* __restrict__ sel01,
                                int* __restrict__ list_c, int* __restrict__ posg,
                                int* __restrict__ cnt, int* __restrict__ basearr)
{
    __shared__ int wbase[16];
    __shared__ int sbase;
    int t = threadIdx.x;
    int lane = t & 63, w = t >> 6;
    int s0 = sel01[2 * t], s1 = sel01[2 * t + 1];
    if (t == 0) sbase = 0;
    __syncthreads();
    for (int e = 0; e < 8; ++e) {
        int flag  = (s0 == e || s1 == e) ? 1 : 0;
        int kslot = (s0 == e) ? 0 : 1;
        unsigned long long m = __ballot(flag);
        int lpre = __popcll(m & ((1ull << lane) - 1ull));
        if (lane == 0) wbase[w] = __popcll(m);
        __syncthreads();
        if (t == 0) {
            int run = sbase;
            basearr[e] = run;
            for (int i = 0; i < 16; ++i) { int tv = wbase[i]; wbase[i] = run; run += tv; }
            cnt[e] = run - sbase;
            sbase = run;
        }
        __syncthreads();
        if (flag) {
            int pos = wbase[w] + lpre;
            list_c[pos] = t;
            posg[2 * t + kslot] = pos;
        }
        __syncthreads();
    }
}

// ------------------------------------------------------------ bf16 casts ----
__global__ void cast_bf16_kernel(const float* __restrict__ x, unsigned short* __restrict__ y)
{
    int i = (blockIdx.x * 256 + threadIdx.x) * 4;
    float4 a = *(const float4*)(x + i);
    ushort4 o;
    o.x = f2bf(a.x); o.y = f2bf(a.y); o.z = f2bf(a.z); o.w = f2bf(a.w);
    *(ushort4*)(y + i) = o;
}

__global__ void gather_cast_kernel(const float* __restrict__ hidden, const int* __restrict__ list,
                                   unsigned short* __restrict__ xe)
{
    int slot = blockIdx.x;
    int tok = list[slot];
    const float* src = hidden + (size_t)tok * Dm;
    unsigned short* dst = xe + (size_t)slot * Dm;
    int c = threadIdx.x * 8;
    float4 a = *(const float4*)(src + c);
    float4 b = *(const float4*)(src + c + 4);
    ushort4 o1, o2;
    o1.x = f2bf(a.x); o1.y = f2bf(a.y); o1.z = f2bf(a.z); o1.w = f2bf(a.w);
    o2.x = f2bf(b.x); o2.y = f2bf(b.y); o2.z = f2bf(b.z); o2.w = f2bf(b.w);
    *(ushort4*)(dst + c) = o1;
    *(ushort4*)(dst + c + 4) = o2;
}

// fp32 [B][K][N] -> bf16 [B][N][K]
__global__ void transpose_cast_kernel(const float* __restrict__ in, unsigned short* __restrict__ out,
                                      int K, int N)
{
    __shared__ float tile[32][33];
    int b = blockIdx.z;
    int k0 = blockIdx.x * 32, n0 = blockIdx.y * 32;
    const float* ip = in + (size_t)b * K * N;
    unsigned short* op = out + (size_t)b * K * N;
    int tx = threadIdx.x & 31, ty = threadIdx.x >> 5;   // 32 x 8
#pragma unroll
    for (int i = 0; i < 4; ++i)
        tile[ty + i * 8][tx] = ip[(size_t)(k0 + ty + i * 8) * N + n0 + tx];
    __syncthreads();
#pragma unroll
    for (int i = 0; i < 4; ++i)
        op[(size_t)(n0 + ty + i * 8) * K + k0 + tx] = f2bf(tile[tx][ty + i * 8]);
}

// ----------------------------------------------------------- bf16 GEMM ------
// C[M][N] = A[M][K] * Bt[N][K]^T, 128x128 tile, BK=32, mfma 16x16x32 bf16.
template<bool EXPERT>
__global__ __launch_bounds__(256)
void gemm_bf16(const unsigned short* __restrict__ A,
               const unsigned short* __restrict__ Bt,
               float* __restrict__ C,
               const int* __restrict__ cnt, const int* __restrict__ basearr,
               int M, int K, int N)
{
    int e = EXPERT ? blockIdx.z : 0;
    int Mloc = M, base = 0;
    if (EXPERT) {
        Mloc = cnt[e]; base = basearr[e];
        if ((int)(blockIdx.x * 128) >= Mloc) return;
    }
    int m0 = blockIdx.x * 128, n0 = blockIdx.y * 128;
    const unsigned short* Ab = A + (size_t)base * K;
    const unsigned short* Bb = Bt + (size_t)e * (size_t)K * N;
    __shared__ unsigned short As[128 * 32];
    __shared__ unsigned short Bs[128 * 32];
    int tid = threadIdx.x;
    int lane = tid & 63, wave = tid >> 6;
    const unsigned short* ga[2];
    const unsigned short* gb[2];
    unsigned short* la[2];
    unsigned short* lb[2];
#pragma unroll
    for (int j = 0; j < 2; ++j) {
        int flat = j * 256 + tid;
        int row = flat >> 2, sub = flat & 3;
        int ar = m0 + row; if (ar > Mloc - 1) ar = Mloc - 1;
        ga[j] = Ab + (size_t)ar * K + sub * 8;
        gb[j] = Bb + (size_t)(n0 + row) * K + sub * 8;
        la[j] = As + flat * 8;
        lb[j] = Bs + flat * 8;
    }
    floatx4 acc[4][4];
#pragma unroll
    for (int i = 0; i < 4; ++i)
#pragma unroll
        for (int j = 0; j < 4; ++j) acc[i][j] = (floatx4){0.f, 0.f, 0.f, 0.f};

    int wm = (wave >> 1) * 64, wn = (wave & 1) * 64;
    int fr = lane & 15, kr = (lane >> 4) * 8;

    for (int k0 = 0; k0 < K; k0 += 32) {
        gl_lds16(ga[0] + k0, la[0]);
        gl_lds16(gb[0] + k0, lb[0]);
        gl_lds16(ga[1] + k0, la[1]);
        gl_lds16(gb[1] + k0, lb[1]);
        __syncthreads();
        bf16x8 af[4], bfr[4];
#pragma unroll
        for (int f = 0; f < 4; ++f) {
            af[f]  = *(const bf16x8*)(As + (size_t)(wm + f * 16 + fr) * 32 + kr);
            bfr[f] = *(const bf16x8*)(Bs + (size_t)(wn + f * 16 + fr) * 32 + kr);
        }
#pragma unroll
        for (int fm = 0; fm < 4; ++fm)
#pragma unroll
            for (int fn = 0; fn < 4; ++fn)
                acc[fm][fn] = __builtin_amdgcn_mfma_f32_16x16x32_bf16(af[fm], bfr[fn], acc[fm][fn], 0, 0, 0);
        __syncthreads();
    }
    int rb = (lane >> 4) * 4;
#pragma unroll
    for (int fm = 0; fm < 4; ++fm) {
#pragma unroll
        for (int r = 0; r < 4; ++r) {
            int m = m0 + wm + fm * 16 + rb + r;
            if (m < Mloc) {
                float* cp = C + (size_t)(base + m) * N + n0 + wn + fr;
#pragma unroll
                for (int fn = 0; fn < 4; ++fn)
                    cp[fn * 16] = acc[fm][fn][r];
            }
        }
    }
}

// ------------------------------------------- beta / g small projections ----
__global__ void ba_kernel(const float* __restrict__ hidden,
                          const float* __restrict__ b_w, const float* __restrict__ a_w,
                          const float* __restrict__ A_log, const float* __restrict__ dt_bias,
                          const int* __restrict__ list, const int* __restrict__ cnt,
                          const int* __restrict__ basearr,
                          float* __restrict__ beta_c, float* __restrict__ g_c)
{
    int j = blockIdx.x, e = blockIdx.y;
    if (j >= cnt[e]) return;
    int gpos = basearr[e] + j;
    int tok = list[gpos];
    int lane = threadIdx.x;                      // 64
    const float* hr = hidden + (size_t)tok * Dm;
    float h[32];
#pragma unroll
    for (int i = 0; i < 32; ++i) h[i] = hr[lane + 64 * i];
    for (int c = 0; c < 12; ++c) {
        int col = c % 6;
        const float* W = ((c < 6) ? b_w : a_w) + (size_t)e * Dm * 6;
        float acc = 0.f;
#pragma unroll
        for (int i = 0; i < 32; ++i) acc += h[i] * W[(size_t)(lane + 64 * i) * 6 + col];
#pragma unroll
        for (int off = 1; off < 64; off <<= 1) acc += __shfl_xor(acc, off, 64);
        if (lane == 0) {
            if (c < 6) {
                beta_c[gpos * 6 + col] = 1.f / (1.f + expf(-acc));
            } else {
                float x = acc + dt_bias[col];
                float sp = (x > 20.f) ? x : log1pf(expf(x));
                g_c[gpos * 6 + col] = -expf(A_log[col]) * sp;
            }
        }
    }
}

// -------------------------------------- causal conv4 + silu (+ l2 norm) ----
template<bool GATHER>
__global__ void conv_norm_kernel(const float* __restrict__ X,
                                 const float* __restrict__ convw,
                                 const int* __restrict__ list, const int* __restrict__ cnt,
                                 const int* __restrict__ basearr,
                                 float* __restrict__ outb, float scale)
{
    int j = blockIdx.x, e = blockIdx.y, h = blockIdx.z;
    if (j >= cnt[e]) return;
    int base = basearr[e];
    int gpos = base + j;
    int c = h * DKk + threadIdx.x;               // 256 threads
    float acc = 0.f;
#pragma unroll
    for (int tau = 0; tau < 4; ++tau) {
        int jj = j - 3 + tau;
        if (jj >= 0) {
            const float* row = GATHER ? (X + (size_t)list[base + jj] * KD)
                                      : (X + (size_t)(base + jj) * KD);
            acc += row[c] * convw[c * 4 + tau];
        }
    }
    float y = acc / (1.f + expf(-acc));          // silu
    float v = y * y;
#pragma unroll
    for (int off = 1; off < 64; off <<= 1) v += __shfl_xor(v, off, 64);
    __shared__ float red[4];
    if ((threadIdx.x & 63) == 0) red[threadIdx.x >> 6] = v;
    __syncthreads();
    float total = red[0] + red[1] + red[2] + red[3];
    outb[(size_t)gpos * KD + c] = y * rsqrtf(total + 1e-6f) * scale;
}

__global__ void conv_v_kernel(const float* __restrict__ X,
                              const float* __restrict__ convw,
                              const int* __restrict__ cnt, const int* __restrict__ basearr,
                              float* __restrict__ outb)
{
    int j = blockIdx.x, e = blockIdx.y;
    if (j >= cnt[e]) return;
    int base = basearr[e];
    int gpos = base + j;
    int c = blockIdx.z * 256 + threadIdx.x;      // 12 * 256 = 3072
    float acc = 0.f;
#pragma unroll
    for (int tau = 0; tau < 4; ++tau) {
        int jj = j - 3 + tau;
        if (jj >= 0) acc += X[(size_t)(base + jj) * VD + c] * convw[c * 4 + tau];
    }
    outb[(size_t)gpos * VD + c] = acc / (1.f + expf(-acc));
}

// --------------------------------------------- gated delta rule (serial) ----
// grid (16, H, E); 256 threads; thread = (kpart 0..7, vcol 0..31), 32 state
// floats/thread. Ping-pong prefetch of next step's k/q/scalars; launch_bounds
// (256,2) caps VGPR at ~256 so nothing spills (R2 spilled at VGPR_Count=48).
__global__ __launch_bounds__(256, 2)
void recurrence_kernel(const float* __restrict__ qn, const float* __restrict__ kn,
                       const float* __restrict__ vc,
                       const float* __restrict__ beta_c, const float* __restrict__ g_c,
                       const int* __restrict__ cnt, const int* __restrict__ basearr,
                       float* __restrict__ o_c)
{
    int vb = blockIdx.x, h = blockIdx.y, e = blockIdx.z;
    int n = cnt[e], base = basearr[e];
    if (n <= 0) return;
    int kpart = threadIdx.x & 7;
    int vcol  = threadIdx.x >> 3;
    int v = vb * 32 + vcol;
    const float* kb = kn + (size_t)base * KD + h * DKk + kpart * 32;
    const float* qb = qn + (size_t)base * KD + h * DKk + kpart * 32;
    const float* vp = vc + (size_t)base * VD + h * DVv + v;
    const float* gp = g_c + (size_t)base * Hh + h;
    const float* bp = beta_c + (size_t)base * Hh + h;
    float* op = o_c + (size_t)base * VD + h * DVv + v;
    float4 s[8];
#pragma unroll
    for (int i = 0; i < 8; ++i) s[i] = make_float4(0.f, 0.f, 0.f, 0.f);

    float4 kA[8], qA[8], kB[8], qB[8];
    float gA, bA, vA, gB, bB, vB;

#define LOADSTEP(K_, Q_, G_, B_, V_, jj) do {                                  \
        const float4* krp_ = (const float4*)(kb + (size_t)(jj) * KD);          \
        const float4* qrp_ = (const float4*)(qb + (size_t)(jj) * KD);          \
        _Pragma("unroll") for (int i_ = 0; i_ < 8; ++i_) {                     \
            K_[i_] = krp_[i_]; Q_[i_] = qrp_[i_]; }                            \
        G_ = gp[(size_t)(jj) * Hh]; B_ = bp[(size_t)(jj) * Hh];                \
        V_ = vp[(size_t)(jj) * VD];                                            \
    } while (0)

    auto compute = [&](const float4 (&kk)[8], const float4 (&qq)[8],
                       float gv, float btv, float vval, int j) {
        float4 pa = make_float4(0.f, 0.f, 0.f, 0.f);
        float4 ra = make_float4(0.f, 0.f, 0.f, 0.f);
        float4 qa = make_float4(0.f, 0.f, 0.f, 0.f);
#pragma unroll
        for (int i = 0; i < 8; ++i) {
            pa.x = fmaf(kk[i].x, s[i].x, pa.x); pa.y = fmaf(kk[i].y, s[i].y, pa.y);
            pa.z = fmaf(kk[i].z, s[i].z, pa.z); pa.w = fmaf(kk[i].w, s[i].w, pa.w);
            ra.x = fmaf(qq[i].x, s[i].x, ra.x); ra.y = fmaf(qq[i].y, s[i].y, ra.y);
            ra.z = fmaf(qq[i].z, s[i].z, ra.z); ra.w = fmaf(qq[i].w, s[i].w, ra.w);
            qa.x = fmaf(qq[i].x, kk[i].x, qa.x); qa.y = fmaf(qq[i].y, kk[i].y, qa.y);
            qa.z = fmaf(qq[i].z, kk[i].z, qa.z); qa.w = fmaf(qq[i].w, kk[i].w, qa.w);
        }
        float p  = (pa.x + pa.y) + (pa.z + pa.w);
        float r  = (ra.x + ra.y) + (ra.z + ra.w);
        float qk = (qa.x + qa.y) + (qa.z + qa.w);
#pragma unroll
        for (int m = 1; m < 8; m <<= 1) {
            p  += __shfl_xor(p,  m, 64);
            r  += __shfl_xor(r,  m, 64);
            qk += __shfl_xor(qk, m, 64);
        }
        float eg = __expf(gv);
        float delta = (vval - p * eg) * btv;
        float out = fmaf(qk, delta, eg * r);
#pragma unroll
        for (int i = 0; i < 8; ++i) {
            s[i].x = fmaf(eg, s[i].x, kk[i].x * delta);
            s[i].y = fmaf(eg, s[i].y, kk[i].y * delta);
            s[i].z = fmaf(eg, s[i].z, kk[i].z * delta);
            s[i].w = fmaf(eg, s[i].w, kk[i].w * delta);
        }
        if (kpart == 0) op[(size_t)j * VD] = out;
    };

    LOADSTEP(kA, qA, gA, bA, vA, 0);
    for (int j = 0; j < n; j += 2) {
        if (j + 1 < n) LOADSTEP(kB, qB, gB, bB, vB, j + 1);
        compute(kA, qA, gA, bA, vA, j);
        if (j + 1 >= n) break;
        if (j + 2 < n) LOADSTEP(kA, qA, gA, bA, vA, j + 2);
        compute(kB, qB, gB, bB, vB, j + 1);
    }
#undef LOADSTEP
}

// ------------------------------- combine + gated RMSNorm (swish gate) -------
__global__ void combine_kernel(const float* __restrict__ o_c, const float* __restrict__ gg,
                               const float* __restrict__ norm_w,
                               const int* __restrict__ posg, const float* __restrict__ w01,
                               unsigned short* __restrict__ ocg)
{
    int t = blockIdx.x, h = blockIdx.y;
    int p0 = posg[2 * t], p1 = posg[2 * t + 1];
    float w0 = w01[2 * t], w1 = w01[2 * t + 1];
    int v0 = threadIdx.x, v1 = threadIdx.x + 256;
    size_t r0 = (size_t)p0 * VD + h * DVv, r1 = (size_t)p1 * VD + h * DVv;
    float a  = w0 * o_c[r0 + v0] + w1 * o_c[r1 + v0];
    float b2 = w0 * o_c[r0 + v1] + w1 * o_c[r1 + v1];
    float val = a * a + b2 * b2;
#pragma unroll
    for (int off = 1; off < 64; off <<= 1) val += __shfl_xor(val, off, 64);
    __shared__ float red[4];
    if ((threadIdx.x & 63) == 0) red[threadIdx.x >> 6] = val;
    __syncthreads();
    float total = red[0] + red[1] + red[2] + red[3];
    float rms = rsqrtf(total / 512.f + 1e-5f);
    size_t og = (size_t)t * VD + h * DVv;
    float g0 = gg[og + v0], g1 = gg[og + v1];
    ocg[og + v0] = f2bf(a  * rms * norm_w[v0] * g0 / (1.f + expf(-g0)));
    ocg[og + v1] = f2bf(b2 * rms * norm_w[v1] * g1 / (1.f + expf(-g1)));
}

// ------------------------------------------------------------------ host ----
extern "C" void kernel_launch(void* const* d_in, const int* in_sizes, int n_in,
                              void* d_out, int out_size, void* d_ws, size_t ws_size,
                              hipStream_t stream)
{
    const float* hidden   = (const float*)d_in[0];
    const float* q_w      = (const float*)d_in[1];
    const float* gate_w   = (const float*)d_in[2];
    const float* k_w      = (const float*)d_in[3];
    const float* v_w      = (const float*)d_in[4];
    const float* b_w      = (const float*)d_in[5];
    const float* a_w      = (const float*)d_in[6];
    const float* A_log    = (const float*)d_in[7];
    const float* dt_bias  = (const float*)d_in[8];
    const float* q_conv_w = (const float*)d_in[9];
    const float* k_conv_w = (const float*)d_in[10];
    const float* v_conv_w = (const float*)d_in[11];
    const float* g_w      = (const float*)d_in[12];
    const float* norm_w   = (const float*)d_in[13];
    const float* o_w      = (const float*)d_in[14];
    float* outp = (float*)d_out;

    float* f = (float*)d_ws;
    size_t off = 0;
    auto alloc = [&](size_t n) { float* p = f + off; off += (n + 3) & ~(size_t)3; return p; };
    float* qh     = alloc((size_t)1024 * 1536);
    float* kraw   = alloc((size_t)2048 * 1536);
    float* qn     = alloc((size_t)2048 * 1536);
    float* kn     = alloc((size_t)2048 * 1536);
    float* vraw   = alloc((size_t)2048 * 3072);   // reused as o_c after conv_v
    float* vconv  = alloc((size_t)2048 * 3072);
    float* gg     = alloc((size_t)1024 * 3072);
    float* beta_c = alloc(2048 * 6);
    float* g_c    = alloc(2048 * 6);
    float* w01f   = alloc(2048);

    unsigned short* u = (unsigned short*)(f + off);
    size_t uoff = 0;
    auto ualloc = [&](size_t n) { unsigned short* p = u + uoff; uoff += (n + 7) & ~(size_t)7; return p; };
    unsigned short* hidden_bf = ualloc((size_t)1024 * 2048);
    unsigned short* xe_c      = ualloc((size_t)2048 * 2048);
    unsigned short* ocg       = ualloc((size_t)1024 * 3072);
    unsigned short* q_wT      = ualloc((size_t)2048 * 1536);
    unsigned short* k_wT      = ualloc((size_t)8 * 2048 * 1536);
    unsigned short* v_wT      = ualloc((size_t)8 * 2048 * 3072);
    unsigned short* g_wT      = ualloc((size_t)2048 * 3072);
    unsigned short* o_wT      = ualloc((size_t)3072 * 2048);

    int* ib      = (int*)(u + uoff);
    int* sel01   = ib;
    int* list_c  = ib + 2048;
    int* posg    = ib + 4096;
    int* cnt     = ib + 6144;
    int* basearr = ib + 6152;
    float* o_c = vraw;

    router_kernel<<<1024, 64, 0, stream>>>(hidden, gate_w, sel01, w01f);
    dispatch_kernel<<<1, 1024, 0, stream>>>(sel01, list_c, posg, cnt, basearr);

    cast_bf16_kernel<<<2048, 256, 0, stream>>>(hidden, hidden_bf);
    gather_cast_kernel<<<2048, 256, 0, stream>>>(hidden, list_c, xe_c);
    transpose_cast_kernel<<<dim3(64, 48, 1), 256, 0, stream>>>(q_w, q_wT, 2048, 1536);
    transpose_cast_kernel<<<dim3(64, 48, 8), 256, 0, stream>>>(k_w, k_wT, 2048, 1536);
    transpose_cast_kernel<<<dim3(64, 96, 8), 256, 0, stream>>>(v_w, v_wT, 2048, 3072);
    transpose_cast_kernel<<<dim3(64, 96, 1), 256, 0, stream>>>(g_w, g_wT, 2048, 3072);
    transpose_cast_kernel<<<dim3(96, 64, 1), 256, 0, stream>>>(o_w, o_wT, 3072, 2048);

    gemm_bf16<false><<<dim3(8, 12), 256, 0, stream>>>(hidden_bf, q_wT, qh, nullptr, nullptr, 1024, 2048, 1536);
    gemm_bf16<true ><<<dim3(8, 12, 8), 256, 0, stream>>>(xe_c, k_wT, kraw, cnt, basearr, 0, 2048, 1536);
    gemm_bf16<true ><<<dim3(8, 24, 8), 256, 0, stream>>>(xe_c, v_wT, vraw, cnt, basearr, 0, 2048, 3072);
    gemm_bf16<false><<<dim3(8, 24), 256, 0, stream>>>(hidden_bf, g_wT, gg, nullptr, nullptr, 1024, 2048, 3072);

    ba_kernel<<<dim3(1024, 8), 64, 0, stream>>>(hidden, b_w, a_w, A_log, dt_bias,
                                                list_c, cnt, basearr, beta_c, g_c);

    conv_norm_kernel<true ><<<dim3(1024, 8, 6), 256, 0, stream>>>(qh,   q_conv_w, list_c, cnt, basearr, qn, 0.0625f);
    conv_norm_kernel<false><<<dim3(1024, 8, 6), 256, 0, stream>>>(kraw, k_conv_w, list_c, cnt, basearr, kn, 1.0f);
    conv_v_kernel<<<dim3(1024, 8, 12), 256, 0, stream>>>(vraw, v_conv_w, cnt, basearr, vconv);

    recurrence_kernel<<<dim3(16, 6, 8), 256, 0, stream>>>(qn, kn, vconv, beta_c, g_c,
                                                          cnt, basearr, o_c);

    combine_kernel<<<dim3(1024, 6), 256, 0, stream>>>(o_c, gg, norm_w, posg, w01f, ocg);
    gemm_bf16<false><<<dim3(8, 16), 256, 0, stream>>>(ocg, o_wT, outp, nullptr, nullptr, 1024, 3072, 2048);
}